// Round 13
// baseline (883.208 us; speedup 1.0000x reference)
//
#include <hip/hip_runtime.h>
#include <hip/hip_bf16.h>
#include <math.h>

#define L_ 6
#define D_ 768
#define H_ 12
#define DK_ 64
#define DFF_ 3072
#define NB_ 32
#define MAXDIST_ 128
#define B_ 8
#define S_ 512
#define NEG_ (-1e9f)
#define BS_ (B_*S_)            // 4096 rows
#define BSD_ ((size_t)BS_*D_)  // 3,145,728 elements
#define WLAYER_ 7077888        // weight elements per layer (4*589824 + 2*2359296)

typedef __bf16 bf16x8 __attribute__((ext_vector_type(8)));
typedef float f32x4 __attribute__((ext_vector_type(4)));

__device__ __forceinline__ unsigned short f2bf(float f) {
    unsigned u = __float_as_uint(f);
    u += 0x7fff + ((u >> 16) & 1);          // RNE
    return (unsigned short)(u >> 16);
}
__device__ __forceinline__ float bf2f(unsigned short s) {
    return __uint_as_float(((unsigned)s) << 16);
}

#define GLDS(g, l) __builtin_amdgcn_global_load_lds( \
    (const __attribute__((address_space(1))) void*)(const void*)(g), \
    (__attribute__((address_space(3))) void*)(void*)(l), 16, 0, 0)

// ---------------- embedding gather ----------------
__global__ __launch_bounds__(192) void k_embed(const int* __restrict__ ids,
                                               const float* __restrict__ ew,
                                               float* __restrict__ h) {
    int row = blockIdx.x;
    int id = ids[row];
    const float4* src = (const float4*)(ew + (size_t)id * D_);
    float4* dst = (float4*)(h + (size_t)row * D_);
    dst[threadIdx.x] = src[threadIdx.x];
}

// ---------------- T5 RMSNorm (vectorized float4 path) ----------------
template<int OUTBF>
__global__ __launch_bounds__(256) void k_rmsnorm(const float* __restrict__ in,
                                                 const float* __restrict__ w,
                                                 void* __restrict__ outp) {
    int row = blockIdx.x;
    int tid = threadIdx.x;
    const float4* x4 = (const float4*)(in + (size_t)row * D_);
    float4 v = make_float4(0.f, 0.f, 0.f, 0.f);
    if (tid < 192) v = x4[tid];
    float ss = v.x * v.x + v.y * v.y + v.z * v.z + v.w * v.w;
    #pragma unroll
    for (int off = 32; off; off >>= 1) ss += __shfl_down(ss, off, 64);
    __shared__ float sbuf[4];
    if ((tid & 63) == 0) sbuf[tid >> 6] = ss;
    __syncthreads();
    float tot = sbuf[0] + sbuf[1] + sbuf[2] + sbuf[3];
    float scale = rsqrtf(tot / (float)D_ + 1e-6f);
    if (tid < 192) {
        float4 wv = ((const float4*)w)[tid];
        float o0 = wv.x * v.x * scale, o1 = wv.y * v.y * scale;
        float o2 = wv.z * v.z * scale, o3 = wv.w * v.w * scale;
        if (OUTBF) {
            ushort4 u;
            u.x = f2bf(o0); u.y = f2bf(o1); u.z = f2bf(o2); u.w = f2bf(o3);
            ((ushort4*)outp)[(size_t)row * 192 + tid] = u;
        } else {
            ((float4*)outp)[(size_t)row * 192 + tid] = make_float4(o0, o1, o2, o3);
        }
    }
}

// ---------------- relative position bias, [h][q][key] bf16 ----------------
__global__ __launch_bounds__(256) void k_posbias(const float* __restrict__ rbw,
                                                 unsigned short* __restrict__ biasg) {
    int idx = blockIdx.x * 256 + threadIdx.x;
    if (idx >= S_ * S_) return;
    int q = idx / S_, key = idx - q * S_;
    int rel = key - q;                           // memory - query
    const int nb = NB_ / 2;                      // 16
    int ret = rel > 0 ? nb : 0;
    int n = rel < 0 ? -rel : rel;
    const int max_exact = nb / 2;                // 8
    int val;
    if (n < max_exact) {
        val = n;
    } else {
        float lf = logf((float)n / (float)max_exact) /
                   logf((float)MAXDIST_ / (float)max_exact) * (float)(nb - max_exact);
        val = max_exact + (int)lf;
        if (val > nb - 1) val = nb - 1;
    }
    int bucket = ret + val;
    #pragma unroll
    for (int hh = 0; hh < H_; ++hh)
        biasg[((size_t)hh * S_ + q) * S_ + key] = f2bf(rbw[bucket * H_ + hh]);
}

// ---------------- ALL layers weight fp32 -> bf16 (NT loads, 1 chunk/thread) ----------------
#define W1V4 147456   // 589824/4
#define W2V4 589824   // 2359296/4
#define WLV4 1769472  // WLAYER_/4
__global__ __launch_bounds__(256) void k_wconv_all(const float* __restrict__ qw,
                                                   const float* __restrict__ kw,
                                                   const float* __restrict__ vw,
                                                   const float* __restrict__ ow,
                                                   const float* __restrict__ wiw,
                                                   const float* __restrict__ wow,
                                                   unsigned short* __restrict__ wb) {
    int gid = blockIdx.x * 256 + threadIdx.x;     // over L_*WLV4
    int l = gid / WLV4;
    int i = gid - l * WLV4;
    const float* src;
    if (i < W1V4)                src = qw  + (size_t)l * 589824;
    else if ((i -= W1V4) < W1V4) src = kw  + (size_t)l * 589824;
    else if ((i -= W1V4) < W1V4) src = vw  + (size_t)l * 589824;
    else if ((i -= W1V4) < W1V4) src = ow  + (size_t)l * 589824;
    else if ((i -= W1V4) < W2V4) src = wiw + (size_t)l * 2359296;
    else { i -= W2V4;            src = wow + (size_t)l * 2359296; }
    // NT load via ext_vector_type (builtin rejects HIP_vector_type)
    f32x4 a = __builtin_nontemporal_load(((const f32x4*)src) + i);
    ushort4 o4;
    o4.x = f2bf(a[0]); o4.y = f2bf(a[1]); o4.z = f2bf(a[2]); o4.w = f2bf(a[3]);
    ((ushort4*)wb)[gid] = o4;                     // normal store: wb is re-read by GEMMs
}

// ---------------- 3-stage double^1.5-buffered MFMA GEMM core (BMxBN, BK=64, NT) ----------------
template<int BM, int BN>
__device__ __forceinline__ void stage_tile_t(const unsigned short* __restrict__ Abase,
                                             const unsigned short* __restrict__ Bbase,
                                             int k0, int K, int buf,
                                             unsigned short* lsA, unsigned short* lsB,
                                             int w, int lane) {
    constexpr int CA = BM / 32, CB = BN / 32;
    #pragma unroll
    for (int c = 0; c < CA; ++c) {
        int off = c * 4096 + w * 1024 + lane * 16;     // byte offset in BM*128 half-tile
        int row = off >> 7;
        int sc = (off & 127) ^ ((row & 7) << 4);       // pre-swizzled source col (bytes)
        GLDS(Abase + (size_t)row * K + k0 + (sc >> 1), (char*)lsA + buf * (BM * 128) + off);
    }
    #pragma unroll
    for (int c = 0; c < CB; ++c) {
        int off = c * 4096 + w * 1024 + lane * 16;
        int row = off >> 7;
        int sc = (off & 127) ^ ((row & 7) << 4);
        GLDS(Bbase + (size_t)row * K + k0 + (sc >> 1), (char*)lsB + buf * (BN * 128) + off);
    }
}

template<int BM, int BN>
__device__ __forceinline__ void gemm_compute_t(const char* cA, const char* cB,
                                               f32x4 acc[BM / 32][BN / 32],
                                               int l15, int l4, int wr, int wc) {
    constexpr int MI = BM / 32, NJ = BN / 32;
    #pragma unroll
    for (int kk = 0; kk < 2; ++kk) {
        bf16x8 af[MI], bfr[NJ];
        int kByte = kk * 64 + l4 * 16;
        #pragma unroll
        for (int i = 0; i < MI; ++i) {
            int r = wr + i * 16 + l15;
            af[i] = *(const bf16x8*)(cA + r * 128 + (kByte ^ ((r & 7) << 4)));
        }
        #pragma unroll
        for (int j = 0; j < NJ; ++j) {
            int r = wc + j * 16 + l15;
            bfr[j] = *(const bf16x8*)(cB + r * 128 + (kByte ^ ((r & 7) << 4)));
        }
        #pragma unroll
        for (int i = 0; i < MI; ++i)
            #pragma unroll
            for (int j = 0; j < NJ; ++j)
                acc[i][j] = __builtin_amdgcn_mfma_f32_16x16x32_bf16(af[i], bfr[j], acc[i][j], 0, 0, 0);
    }
}

// 3-stage: prologue stages tiles 0,1; iter t stages t+2, waits vmcnt(2*NL) -> tile t landed.
template<int BM, int BN>
__device__ __forceinline__ void gemm_core_t(const unsigned short* __restrict__ A,
                                            const unsigned short* __restrict__ Bw,
                                            int K, int bm, int bn,
                                            unsigned short* lsA, unsigned short* lsB,
                                            f32x4 acc[BM / 32][BN / 32]) {
    int t = threadIdx.x, lane = t & 63, w = t >> 6;
    int l15 = lane & 15, l4 = lane >> 4;
    int wr = (w >> 1) * (BM / 2), wc = (w & 1) * (BN / 2);
    const unsigned short* Abase = A + (size_t)(bm * BM) * K;
    const unsigned short* Bbase = Bw + (size_t)(bn * BN) * K;
    int nt = K >> 6;
    constexpr int NL = BM / 32 + BN / 32;   // loads per stage

    stage_tile_t<BM, BN>(Abase, Bbase, 0, K, 0, lsA, lsB, w, lane);
    stage_tile_t<BM, BN>(Abase, Bbase, 64, K, 1, lsA, lsB, w, lane);
    for (int tq = 0; tq < nt; ++tq) {
        if (tq + 2 < nt)
            stage_tile_t<BM, BN>(Abase, Bbase, (tq + 2) << 6, K, (tq + 2) % 3, lsA, lsB, w, lane);
        int rem = nt - 1 - tq;                  // staged tiles still in flight beyond cur
        static_assert(BM / 32 + BN / 32 == 4 || BM / 32 + BN / 32 == 8, "NL dispatch");
        if constexpr (NL == 4) {
            if (rem >= 2)      asm volatile("s_waitcnt vmcnt(8)" ::: "memory");
            else if (rem == 1) asm volatile("s_waitcnt vmcnt(4)" ::: "memory");
            else               asm volatile("s_waitcnt vmcnt(0)" ::: "memory");
        } else {
            if (rem >= 2)      asm volatile("s_waitcnt vmcnt(16)" ::: "memory");
            else if (rem == 1) asm volatile("s_waitcnt vmcnt(8)" ::: "memory");
            else               asm volatile("s_waitcnt vmcnt(0)" ::: "memory");
        }
        __builtin_amdgcn_s_barrier();
        int cur = tq % 3;
        gemm_compute_t<BM, BN>((const char*)lsA + cur * (BM * 128),
                               (const char*)lsB + cur * (BN * 128), acc, l15, l4, wr, wc);
        asm volatile("s_waitcnt lgkmcnt(0)" ::: "memory");   // my reads of cur done
        __builtin_amdgcn_s_barrier();                         // all reads done before restage
    }
}

// epilogue via LDS transpose -> full-width coalesced C I/O
template<int BM, int BN, int RES, int RELU, int OUTBF>
__global__ __launch_bounds__(256) void k_gemm_t(const unsigned short* __restrict__ A,
                                                const unsigned short* __restrict__ Bw,
                                                const float* __restrict__ res,
                                                void* __restrict__ C, int N, int K) {
    constexpr int SMEMB = 3 * (BM + BN) * 64 * 2;   // 3-stage staging; >= BM*(BN+4)*4
    __shared__ __align__(16) char smem[SMEMB];
    unsigned short* lsA = (unsigned short*)smem;
    unsigned short* lsB = lsA + 3 * BM * 64;
    f32x4 acc[BM / 32][BN / 32] = {};
    int bm = blockIdx.x, bn = blockIdx.y;
    gemm_core_t<BM, BN>(A, Bw, K, bm, bn, lsA, lsB, acc);

    int t = threadIdx.x, lane = t & 63, w = t >> 6;
    int l15 = lane & 15, l4 = lane >> 4;
    int wr = (w >> 1) * (BM / 2), wc = (w & 1) * (BN / 2);
    constexpr int BNP = BN + 4;
    float* cb = (float*)smem;
    __syncthreads();                 // staging buffers dead everywhere
    #pragma unroll
    for (int i = 0; i < BM / 32; ++i)
        #pragma unroll
        for (int r = 0; r < 4; ++r)
            #pragma unroll
            for (int j = 0; j < BN / 32; ++j)
                cb[(wr + i * 16 + l4 * 4 + r) * BNP + wc + j * 16 + l15] = acc[i][j][r];
    __syncthreads();
    constexpr int F4R = BN / 4;      // float4 per row
    constexpr int RPP = 256 / F4R;   // rows per pass
    int rr = t / F4R, cc = t - rr * F4R;
    #pragma unroll
    for (int p = 0; p < BM / RPP; ++p) {
        int row = p * RPP + rr;
        float4 v = *(float4*)&cb[row * BNP + cc * 4];
        size_t gr = (size_t)(bm * BM + row) * N + bn * BN + cc * 4;
        if (RES) {
            float4 rv = *(const float4*)&res[gr];
            v.x += rv.x; v.y += rv.y; v.z += rv.z; v.w += rv.w;
        }
        if (RELU) {
            v.x = fmaxf(v.x, 0.f); v.y = fmaxf(v.y, 0.f);
            v.z = fmaxf(v.z, 0.f); v.w = fmaxf(v.w, 0.f);
        }
        if (OUTBF) {
            ushort4 u;
            u.x = f2bf(v.x); u.y = f2bf(v.y); u.z = f2bf(v.z); u.w = f2bf(v.w);
            *(ushort4*)((unsigned short*)C + gr) = u;
        } else {
            *(float4*)((float*)C + gr) = v;
        }
    }
}

// QKV (64x64 tile, 3-stage): z=0 -> q bf16 [B,S,768], z=1 -> k, z=2 -> V^T bf16 [B*H,64,512]
__global__ __launch_bounds__(256) void k_gemm_qkv_bf(const unsigned short* __restrict__ X,
                                                     const unsigned short* __restrict__ wq,
                                                     const unsigned short* __restrict__ wk,
                                                     const unsigned short* __restrict__ wv,
                                                     unsigned short* __restrict__ qo,
                                                     unsigned short* __restrict__ ko,
                                                     unsigned short* __restrict__ vt) {
    __shared__ __align__(16) char smem[3 * 128 * 64 * 2];   // 48KB staging; cbuf needs 17.4KB
    unsigned short* lsA = (unsigned short*)smem;
    unsigned short* lsB = lsA + 3 * 64 * 64;
    f32x4 acc[2][2] = {};
    int z = blockIdx.z;
    const unsigned short* Bm = z == 0 ? wq : (z == 1 ? wk : wv);
    int bm = blockIdx.x, bn = blockIdx.y;
    gemm_core_t<64, 64>(X, Bm, D_, bm, bn, lsA, lsB, acc);
    int t = threadIdx.x, lane = t & 63, w = t >> 6;
    int l15 = lane & 15, l4 = lane >> 4;
    int wr = (w >> 1) * 32, wc = (w & 1) * 32;
    if (z < 2) {
        unsigned short* C = z == 0 ? qo : ko;
        constexpr int BNP = 68;
        float* cb = (float*)smem;
        __syncthreads();
        #pragma unroll
        for (int i = 0; i < 2; ++i)
            #pragma unroll
            for (int r = 0; r < 4; ++r)
                #pragma unroll
                for (int j = 0; j < 2; ++j)
                    cb[(wr + i * 16 + l4 * 4 + r) * BNP + wc + j * 16 + l15] = acc[i][j][r];
        __syncthreads();
        int rr = t >> 4, cc = t & 15;            // 16 f4 per row, 16 rows per pass
        #pragma unroll
        for (int p = 0; p < 4; ++p) {
            int row = p * 16 + rr;
            float4 v = *(float4*)&cb[row * BNP + cc * 4];
            size_t gr = (size_t)(bm * 64 + row) * D_ + bn * 64 + cc * 4;
            ushort4 u;
            u.x = f2bf(v.x); u.y = f2bf(v.y); u.z = f2bf(v.z); u.w = f2bf(v.w);
            *(ushort4*)(C + gr) = u;
        }
    } else {
        // V^T: vt[((b*H + h)*64 + dv)*512 + s]; bn*64 spans exactly head bn
        #pragma unroll
        for (int i = 0; i < 2; ++i) {
            int row0 = bm * 64 + wr + i * 16 + l4 * 4;
            int b = row0 >> 9, s0 = row0 & 511;
            #pragma unroll
            for (int j = 0; j < 2; ++j) {
                int col = bn * 64 + wc + j * 16 + l15;
                int hh = col >> 6, dv = col & 63;
                ushort4 o4;
                o4.x = f2bf(acc[i][j][0]); o4.y = f2bf(acc[i][j][1]);
                o4.z = f2bf(acc[i][j][2]); o4.w = f2bf(acc[i][j][3]);
                *(ushort4*)(vt + (((size_t)b * H_ + hh) * 64 + dv) * S_ + s0) = o4;
            }
        }
    }
}

// ---------------- MFMA flash attention ----------------
// 2-deep K/V LDS pipeline; bias regs pipelined one tile ahead; mask folded to emask LDS.
__global__ __launch_bounds__(256) void k_attn_flash(const unsigned short* __restrict__ qb,
                                                    const unsigned short* __restrict__ kb,
                                                    const unsigned short* __restrict__ vtb,
                                                    const unsigned short* __restrict__ biasg,
                                                    const float* __restrict__ mask,
                                                    unsigned short* __restrict__ ctx) {
    __shared__ __align__(16) unsigned short Kt[2][64 * 64];
    __shared__ __align__(16) unsigned short Vt[2][64 * 64];
    __shared__ __align__(16) unsigned short Pt[4][16 * 64];
    __shared__ __align__(16) float emask[S_];

    int t = threadIdx.x, lane = t & 63, w = t >> 6;
    int l15 = lane & 15, l4 = lane >> 4;
    int bh = blockIdx.y;
    int b = bh / H_, hh = bh - b * H_;
    int qblk = blockIdx.x;
    int qloc = w * 16 + l15;
    int qg = qblk * 64 + qloc;

    bf16x8 qf[2];
    {
        const unsigned short* qp = qb + ((size_t)(b * S_ + qg)) * D_ + hh * DK_;
        qf[0] = *(const bf16x8*)(qp + l4 * 8);
        qf[1] = *(const bf16x8*)(qp + 32 + l4 * 8);
    }
    float mrun = -1e30f, lsum = 0.f;
    f32x4 cacc[4] = {};

    auto stage_kv = [&](int kt, int buf) {
        int kbase = kt * 64;
        #pragma unroll
        for (int c = 0; c < 2; ++c) {
            int off = (w * 2 + c) * 1024 + lane * 16;
            int row = off >> 7;
            int colb = (off & 127) ^ ((row & 7) << 4);
            GLDS(kb + ((size_t)(b * S_ + kbase + row)) * D_ + hh * DK_ + (colb >> 1),
                 (char*)Kt[buf] + off);
            GLDS(vtb + ((size_t)bh * 64 + row) * S_ + kbase + (colb >> 1),
                 (char*)Vt[buf] + off);
        }
    };

    const unsigned short* bprow = biasg + ((size_t)hh * S_ + qblk * 64 + qloc) * S_;

    stage_kv(0, 0);
    if (t < 128) {
        float4 m = ((const float4*)(mask + (size_t)b * S_))[t];
        float4 e;
        e.x = (1.f - m.x) * NEG_; e.y = (1.f - m.y) * NEG_;
        e.z = (1.f - m.z) * NEG_; e.w = (1.f - m.w) * NEG_;
        *(float4*)&emask[t * 4] = e;
    }
    ushort4 bnxt[4];
    #pragma unroll
    for (int j = 0; j < 4; ++j)
        bnxt[j] = *(const ushort4*)(bprow + j * 16 + l4 * 4);
    asm volatile("s_waitcnt lgkmcnt(0)" ::: "memory");   // emask writes done
    __builtin_amdgcn_s_barrier();

    constexpr int NT = S_ / 64;
    for (int kt = 0; kt < NT; ++kt) {
        int cur = kt & 1;
        int kbase = kt * 64;
        ushort4 bcur[4];
        #pragma unroll
        for (int j = 0; j < 4; ++j) bcur[j] = bnxt[j];

        if (kt < NT - 1) {
            stage_kv(kt + 1, cur ^ 1);
            asm volatile("s_waitcnt vmcnt(4)" ::: "memory");
        } else {
            asm volatile("s_waitcnt vmcnt(0)" ::: "memory");
        }
        __builtin_amdgcn_s_barrier();
        if (kt < NT - 1) {
            #pragma unroll
            for (int j = 0; j < 4; ++j)
                bnxt[j] = *(const ushort4*)(bprow + (kt + 1) * 64 + j * 16 + l4 * 4);
        }

        f32x4 sc[4] = {};
        __builtin_amdgcn_s_setprio(1);
        #pragma unroll
        for (int kk = 0; kk < 2; ++kk) {
            int kByte = kk * 64 + l4 * 16;
            #pragma unroll
            for (int j = 0; j < 4; ++j) {
                int r = j * 16 + l15;
                bf16x8 kf = *(const bf16x8*)((const char*)Kt[cur] + r * 128 + (kByte ^ ((r & 7) << 4)));
                sc[j] = __builtin_amdgcn_mfma_f32_16x16x32_bf16(kf, qf[kk], sc[j], 0, 0, 0);
            }
        }
        __builtin_amdgcn_s_setprio(0);

        float sv[4][4];
        float tmax = -1e30f;
        #pragma unroll
        for (int j = 0; j < 4; ++j) {
            float4 e4 = *(const float4*)&emask[kbase + j * 16 + l4 * 4];
            sv[j][0] = sc[j][0] + bf2f(bcur[j].x) + e4.x;
            sv[j][1] = sc[j][1] + bf2f(bcur[j].y) + e4.y;
            sv[j][2] = sc[j][2] + bf2f(bcur[j].z) + e4.z;
            sv[j][3] = sc[j][3] + bf2f(bcur[j].w) + e4.w;
            tmax = fmaxf(tmax, fmaxf(fmaxf(sv[j][0], sv[j][1]), fmaxf(sv[j][2], sv[j][3])));
        }
        tmax = fmaxf(tmax, __shfl_xor(tmax, 16, 64));
        tmax = fmaxf(tmax, __shfl_xor(tmax, 32, 64));
        float mnew = fmaxf(mrun, tmax);
        float scal = __expf(mrun - mnew);
        #pragma unroll
        for (int i = 0; i < 4; ++i) {
            cacc[i][0] *= scal; cacc[i][1] *= scal;
            cacc[i][2] *= scal; cacc[i][3] *= scal;
        }
        float psum = 0.f;
        unsigned pp[8];
        #pragma unroll
        for (int j = 0; j < 4; ++j) {
            float p0 = __expf(sv[j][0] - mnew), p1 = __expf(sv[j][1] - mnew);
            float p2 = __expf(sv[j][2] - mnew), p3 = __expf(sv[j][3] - mnew);
            psum += (p0 + p1) + (p2 + p3);
            pp[j * 2]     = (unsigned)f2bf(p0) | ((unsigned)f2bf(p1) << 16);
            pp[j * 2 + 1] = (unsigned)f2bf(p2) | ((unsigned)f2bf(p3) << 16);
        }
        lsum = lsum * scal + psum;
        mrun = mnew;
        unsigned short* P = Pt[w];
        #pragma unroll
        for (int j = 0; j < 4; ++j) {
            int base = l15 * 128 + ((j * 32 + l4 * 8) ^ ((l15 & 7) << 4));
            *(unsigned*)((char*)P + base) = pp[j * 2];
            *(unsigned*)((char*)P + base + 4) = pp[j * 2 + 1];
        }
        __builtin_amdgcn_s_setprio(1);
        #pragma unroll
        for (int kk = 0; kk < 2; ++kk) {
            int kByte = kk * 64 + l4 * 16;
            bf16x8 pf = *(const bf16x8*)((const char*)P + l15 * 128 + (kByte ^ ((l15 & 7) << 4)));
            #pragma unroll
            for (int i = 0; i < 4; ++i) {
                int rr = i * 16 + l15;
                bf16x8 vf = *(const bf16x8*)((const char*)Vt[cur] + rr * 128 + (kByte ^ ((rr & 7) << 4)));
                cacc[i] = __builtin_amdgcn_mfma_f32_16x16x32_bf16(vf, pf, cacc[i], 0, 0, 0);
            }
        }
        __builtin_amdgcn_s_setprio(0);
        asm volatile("s_waitcnt lgkmcnt(0)" ::: "memory");
        __builtin_amdgcn_s_barrier();
    }
    lsum += __shfl_xor(lsum, 16, 64);
    lsum += __shfl_xor(lsum, 32, 64);
    float inv = 1.f / lsum;
    unsigned short* cp = ctx + ((size_t)(b * S_ + qg)) * D_ + hh * DK_;
    #pragma unroll
    for (int i = 0; i < 4; ++i) {
        ushort4 o4;
        o4.x = f2bf(cacc[i][0] * inv); o4.y = f2bf(cacc[i][1] * inv);
        o4.z = f2bf(cacc[i][2] * inv); o4.w = f2bf(cacc[i][3] * inv);
        *(ushort4*)(cp + i * 16 + l4 * 4) = o4;
    }
}

// ---------------- launcher ----------------
extern "C" void kernel_launch(void* const* d_in, const int* in_sizes, int n_in,
                              void* d_out, int out_size, void* d_ws, size_t ws_size,
                              hipStream_t stream) {
    const int*   ids  = (const int*)d_in[0];
    const float* mask = (const float*)d_in[1];
    const float* ew   = (const float*)d_in[2];
    const float* ln1  = (const float*)d_in[3];
    const float* qw   = (const float*)d_in[4];
    const float* kw   = (const float*)d_in[5];
    const float* vw   = (const float*)d_in[6];
    const float* rbw  = (const float*)d_in[7];
    const float* ow   = (const float*)d_in[8];
    const float* ln2  = (const float*)d_in[9];
    const float* wiw  = (const float*)d_in[10];
    const float* wow  = (const float*)d_in[11];
    const float* flnw = (const float*)d_in[12];
    float* out = (float*)d_out;

    // ws layout (~136 MB of ~385 MB): h | biasg | wball(6 layers) | xbf(=ctxb) | qbB kbB vtb [+tail]
    char* p = (char*)d_ws;
    float* h = (float*)p;                        p += BSD_ * 4;
    unsigned short* biasg = (unsigned short*)p;  p += (size_t)H_ * S_ * S_ * 2;
    unsigned short* wball = (unsigned short*)p;  p += (size_t)L_ * WLAYER_ * 2;
    unsigned short* xbf   = (unsigned short*)p;  p += BSD_ * 2;
    unsigned short* ctxb  = xbf;                 // aliased: disjoint lifetimes
    unsigned short* qbB   = (unsigned short*)p;  p += BSD_ * 2;
    unsigned short* kbB   = (unsigned short*)p;  p += BSD_ * 2;
    unsigned short* vtb   = (unsigned short*)p;  p += BSD_ * 2;
    /* extra 6.3MB tail for ff */                p += BSD_ * 2;
    unsigned short* ff    = qbB;                 // 25.2MB spans qbB..tail, dead by FFN

    k_embed<<<BS_, 192, 0, stream>>>(ids, ew, h);
    k_posbias<<<(S_ * S_ + 255) / 256, 256, 0, stream>>>(rbw, biasg);
    k_wconv_all<<<(L_ * WLV4) / 256, 256, 0, stream>>>(qw, kw, vw, ow, wiw, wow, wball);

    for (int l = 0; l < L_; ++l) {
        const unsigned short* wl  = wball + (size_t)l * WLAYER_;
        const unsigned short* wq  = wl;
        const unsigned short* wk  = wl + 589824;
        const unsigned short* wv  = wl + 1179648;
        const unsigned short* wo  = wl + 1769472;
        const unsigned short* wwi = wl + 2359296;
        const unsigned short* wwo = wl + 4718592;

        k_rmsnorm<1><<<BS_, 256, 0, stream>>>(h, ln1 + (size_t)l * D_, xbf);
        k_gemm_qkv_bf<<<dim3(BS_ / 64, D_ / 64, 3), 256, 0, stream>>>(
            xbf, wq, wk, wv, qbB, kbB, vtb);
        k_attn_flash<<<dim3(S_ / 64, B_ * H_), 256, 0, stream>>>(
            qbB, kbB, vtb, biasg, mask, ctxb);
        k_gemm_t<64, 64, 1, 0, 0><<<dim3(BS_ / 64, D_ / 64), 256, 0, stream>>>(
            ctxb, wo, h, h, D_, D_);
        k_rmsnorm<1><<<BS_, 256, 0, stream>>>(h, ln2 + (size_t)l * D_, xbf);
        k_gemm_t<64, 64, 0, 1, 1><<<dim3(BS_ / 64, DFF_ / 64), 256, 0, stream>>>(
            xbf, wwi, nullptr, ff, DFF_, D_);
        k_gemm_t<64, 64, 1, 0, 0><<<dim3(BS_ / 64, D_ / 64), 256, 0, stream>>>(
            ff, wwo, h, h, D_, DFF_);
    }
    k_rmsnorm<0><<<BS_, 256, 0, stream>>>(h, flnw, out);
}

// Round 14
// 832.158 us; speedup vs baseline: 1.0613x; 1.0613x over previous
//
#include <hip/hip_runtime.h>
#include <hip/hip_bf16.h>
#include <math.h>

#define L_ 6
#define D_ 768
#define H_ 12
#define DK_ 64
#define DFF_ 3072
#define NB_ 32
#define MAXDIST_ 128
#define B_ 8
#define S_ 512
#define NEG_ (-1e9f)
#define BS_ (B_*S_)            // 4096 rows
#define BSD_ ((size_t)BS_*D_)  // 3,145,728 elements
#define WLAYER_ 7077888        // weight elements per layer (4*589824 + 2*2359296)

typedef __bf16 bf16x8 __attribute__((ext_vector_type(8)));
typedef float f32x4 __attribute__((ext_vector_type(4)));

__device__ __forceinline__ unsigned short f2bf(float f) {
    unsigned u = __float_as_uint(f);
    u += 0x7fff + ((u >> 16) & 1);          // RNE
    return (unsigned short)(u >> 16);
}
__device__ __forceinline__ float bf2f(unsigned short s) {
    return __uint_as_float(((unsigned)s) << 16);
}

#define GLDS(g, l) __builtin_amdgcn_global_load_lds( \
    (const __attribute__((address_space(1))) void*)(const void*)(g), \
    (__attribute__((address_space(3))) void*)(void*)(l), 16, 0, 0)

// ---------------- embedding gather ----------------
__global__ __launch_bounds__(192) void k_embed(const int* __restrict__ ids,
                                               const float* __restrict__ ew,
                                               float* __restrict__ h) {
    int row = blockIdx.x;
    int id = ids[row];
    const float4* src = (const float4*)(ew + (size_t)id * D_);
    float4* dst = (float4*)(h + (size_t)row * D_);
    dst[threadIdx.x] = src[threadIdx.x];
}

// ---------------- T5 RMSNorm (vectorized float4 path) ----------------
template<int OUTBF>
__global__ __launch_bounds__(256) void k_rmsnorm(const float* __restrict__ in,
                                                 const float* __restrict__ w,
                                                 void* __restrict__ outp) {
    int row = blockIdx.x;
    int tid = threadIdx.x;
    const float4* x4 = (const float4*)(in + (size_t)row * D_);
    float4 v = make_float4(0.f, 0.f, 0.f, 0.f);
    if (tid < 192) v = x4[tid];
    float ss = v.x * v.x + v.y * v.y + v.z * v.z + v.w * v.w;
    #pragma unroll
    for (int off = 32; off; off >>= 1) ss += __shfl_down(ss, off, 64);
    __shared__ float sbuf[4];
    if ((tid & 63) == 0) sbuf[tid >> 6] = ss;
    __syncthreads();
    float tot = sbuf[0] + sbuf[1] + sbuf[2] + sbuf[3];
    float scale = rsqrtf(tot / (float)D_ + 1e-6f);
    if (tid < 192) {
        float4 wv = ((const float4*)w)[tid];
        float o0 = wv.x * v.x * scale, o1 = wv.y * v.y * scale;
        float o2 = wv.z * v.z * scale, o3 = wv.w * v.w * scale;
        if (OUTBF) {
            ushort4 u;
            u.x = f2bf(o0); u.y = f2bf(o1); u.z = f2bf(o2); u.w = f2bf(o3);
            ((ushort4*)outp)[(size_t)row * 192 + tid] = u;
        } else {
            ((float4*)outp)[(size_t)row * 192 + tid] = make_float4(o0, o1, o2, o3);
        }
    }
}

// ---------------- relative position bias, [h][q][key] bf16 ----------------
__global__ __launch_bounds__(256) void k_posbias(const float* __restrict__ rbw,
                                                 unsigned short* __restrict__ biasg) {
    int idx = blockIdx.x * 256 + threadIdx.x;
    if (idx >= S_ * S_) return;
    int q = idx / S_, key = idx - q * S_;
    int rel = key - q;                           // memory - query
    const int nb = NB_ / 2;                      // 16
    int ret = rel > 0 ? nb : 0;
    int n = rel < 0 ? -rel : rel;
    const int max_exact = nb / 2;                // 8
    int val;
    if (n < max_exact) {
        val = n;
    } else {
        float lf = logf((float)n / (float)max_exact) /
                   logf((float)MAXDIST_ / (float)max_exact) * (float)(nb - max_exact);
        val = max_exact + (int)lf;
        if (val > nb - 1) val = nb - 1;
    }
    int bucket = ret + val;
    #pragma unroll
    for (int hh = 0; hh < H_; ++hh)
        biasg[((size_t)hh * S_ + q) * S_ + key] = f2bf(rbw[bucket * H_ + hh]);
}

// ---------------- ALL layers weight fp32 -> bf16 (NT loads, 1 chunk/thread) ----------------
#define W1V4 147456   // 589824/4
#define W2V4 589824   // 2359296/4
#define WLV4 1769472  // WLAYER_/4
__global__ __launch_bounds__(256) void k_wconv_all(const float* __restrict__ qw,
                                                   const float* __restrict__ kw,
                                                   const float* __restrict__ vw,
                                                   const float* __restrict__ ow,
                                                   const float* __restrict__ wiw,
                                                   const float* __restrict__ wow,
                                                   unsigned short* __restrict__ wb) {
    int gid = blockIdx.x * 256 + threadIdx.x;     // over L_*WLV4
    int l = gid / WLV4;
    int i = gid - l * WLV4;
    const float* src;
    if (i < W1V4)                src = qw  + (size_t)l * 589824;
    else if ((i -= W1V4) < W1V4) src = kw  + (size_t)l * 589824;
    else if ((i -= W1V4) < W1V4) src = vw  + (size_t)l * 589824;
    else if ((i -= W1V4) < W1V4) src = ow  + (size_t)l * 589824;
    else if ((i -= W1V4) < W2V4) src = wiw + (size_t)l * 2359296;
    else { i -= W2V4;            src = wow + (size_t)l * 2359296; }
    // NT load via ext_vector_type (builtin rejects HIP_vector_type)
    f32x4 a = __builtin_nontemporal_load(((const f32x4*)src) + i);
    ushort4 o4;
    o4.x = f2bf(a[0]); o4.y = f2bf(a[1]); o4.z = f2bf(a[2]); o4.w = f2bf(a[3]);
    ((ushort4*)wb)[gid] = o4;                     // normal store: wb is re-read by GEMMs
}

// ---------------- templated double-buffered MFMA GEMM core (BMxBN, BK=64, NT) ----------------
template<int BM, int BN>
__device__ __forceinline__ void stage_tile_t(const unsigned short* __restrict__ Abase,
                                             const unsigned short* __restrict__ Bbase,
                                             int k0, int K, int buf,
                                             unsigned short* lsA, unsigned short* lsB,
                                             int w, int lane) {
    constexpr int CA = BM / 32, CB = BN / 32;
    #pragma unroll
    for (int c = 0; c < CA; ++c) {
        int off = c * 4096 + w * 1024 + lane * 16;     // byte offset in BM*128 half-tile
        int row = off >> 7;
        int sc = (off & 127) ^ ((row & 7) << 4);       // pre-swizzled source col (bytes)
        GLDS(Abase + (size_t)row * K + k0 + (sc >> 1), (char*)lsA + buf * (BM * 128) + off);
    }
    #pragma unroll
    for (int c = 0; c < CB; ++c) {
        int off = c * 4096 + w * 1024 + lane * 16;
        int row = off >> 7;
        int sc = (off & 127) ^ ((row & 7) << 4);
        GLDS(Bbase + (size_t)row * K + k0 + (sc >> 1), (char*)lsB + buf * (BN * 128) + off);
    }
}

template<int BM, int BN>
__device__ __forceinline__ void gemm_compute_t(const char* cA, const char* cB,
                                               f32x4 acc[BM / 32][BN / 32],
                                               int l15, int l4, int wr, int wc) {
    constexpr int MI = BM / 32, NJ = BN / 32;
    #pragma unroll
    for (int kk = 0; kk < 2; ++kk) {
        bf16x8 af[MI], bfr[NJ];
        int kByte = kk * 64 + l4 * 16;
        #pragma unroll
        for (int i = 0; i < MI; ++i) {
            int r = wr + i * 16 + l15;
            af[i] = *(const bf16x8*)(cA + r * 128 + (kByte ^ ((r & 7) << 4)));
        }
        #pragma unroll
        for (int j = 0; j < NJ; ++j) {
            int r = wc + j * 16 + l15;
            bfr[j] = *(const bf16x8*)(cB + r * 128 + (kByte ^ ((r & 7) << 4)));
        }
        #pragma unroll
        for (int i = 0; i < MI; ++i)
            #pragma unroll
            for (int j = 0; j < NJ; ++j)
                acc[i][j] = __builtin_amdgcn_mfma_f32_16x16x32_bf16(af[i], bfr[j], acc[i][j], 0, 0, 0);
    }
}

template<int BM, int BN>
__device__ __forceinline__ void gemm_core_t(const unsigned short* __restrict__ A,
                                            const unsigned short* __restrict__ Bw,
                                            int K, int bm, int bn,
                                            unsigned short* lsA, unsigned short* lsB,
                                            f32x4 acc[BM / 32][BN / 32]) {
    int t = threadIdx.x, lane = t & 63, w = t >> 6;
    int l15 = lane & 15, l4 = lane >> 4;
    int wr = (w >> 1) * (BM / 2), wc = (w & 1) * (BN / 2);
    const unsigned short* Abase = A + (size_t)(bm * BM) * K;
    const unsigned short* Bbase = Bw + (size_t)(bn * BN) * K;
    int nt = K >> 6;
    constexpr int NL = BM / 32 + BN / 32;   // loads per stage

    stage_tile_t<BM, BN>(Abase, Bbase, 0, K, 0, lsA, lsB, w, lane);
    for (int tq = 0; tq < nt - 1; ++tq) {
        int cur = tq & 1;
        stage_tile_t<BM, BN>(Abase, Bbase, (tq + 1) << 6, K, cur ^ 1, lsA, lsB, w, lane);
        if constexpr (NL == 8)      asm volatile("s_waitcnt vmcnt(8)" ::: "memory");
        else if constexpr (NL == 6) asm volatile("s_waitcnt vmcnt(6)" ::: "memory");
        else                        asm volatile("s_waitcnt vmcnt(4)" ::: "memory");
        __builtin_amdgcn_s_barrier();
        gemm_compute_t<BM, BN>((const char*)lsA + cur * (BM * 128),
                               (const char*)lsB + cur * (BN * 128), acc, l15, l4, wr, wc);
        asm volatile("s_waitcnt lgkmcnt(0)" ::: "memory");
        __builtin_amdgcn_s_barrier();
    }
    int cur = (nt - 1) & 1;
    asm volatile("s_waitcnt vmcnt(0)" ::: "memory");
    __builtin_amdgcn_s_barrier();
    gemm_compute_t<BM, BN>((const char*)lsA + cur * (BM * 128),
                           (const char*)lsB + cur * (BN * 128), acc, l15, l4, wr, wc);
}

// epilogue via LDS transpose -> full-width coalesced C I/O
template<int BM, int BN, int RES, int RELU, int OUTBF>
__global__ __launch_bounds__(256) void k_gemm_t(const unsigned short* __restrict__ A,
                                                const unsigned short* __restrict__ Bw,
                                                const float* __restrict__ res,
                                                void* __restrict__ C, int N, int K) {
    constexpr int SMEMB = 2 * (BM + BN) * 64 * 2;   // staging bytes; >= BM*(BN+4)*4
    __shared__ __align__(16) char smem[SMEMB];
    unsigned short* lsA = (unsigned short*)smem;
    unsigned short* lsB = lsA + 2 * BM * 64;
    f32x4 acc[BM / 32][BN / 32] = {};
    int bm = blockIdx.x, bn = blockIdx.y;
    gemm_core_t<BM, BN>(A, Bw, K, bm, bn, lsA, lsB, acc);

    int t = threadIdx.x, lane = t & 63, w = t >> 6;
    int l15 = lane & 15, l4 = lane >> 4;
    int wr = (w >> 1) * (BM / 2), wc = (w & 1) * (BN / 2);
    constexpr int BNP = BN + 4;
    float* cb = (float*)smem;
    __syncthreads();                 // staging buffers dead everywhere
    #pragma unroll
    for (int i = 0; i < BM / 32; ++i)
        #pragma unroll
        for (int r = 0; r < 4; ++r)
            #pragma unroll
            for (int j = 0; j < BN / 32; ++j)
                cb[(wr + i * 16 + l4 * 4 + r) * BNP + wc + j * 16 + l15] = acc[i][j][r];
    __syncthreads();
    constexpr int F4R = BN / 4;      // float4 per row
    constexpr int RPP = 256 / F4R;   // rows per pass
    int rr = t / F4R, cc = t - rr * F4R;
    #pragma unroll
    for (int p = 0; p < BM / RPP; ++p) {
        int row = p * RPP + rr;
        float4 v = *(float4*)&cb[row * BNP + cc * 4];
        size_t gr = (size_t)(bm * BM + row) * N + bn * BN + cc * 4;
        if (RES) {
            float4 rv = *(const float4*)&res[gr];
            v.x += rv.x; v.y += rv.y; v.z += rv.z; v.w += rv.w;
        }
        if (RELU) {
            v.x = fmaxf(v.x, 0.f); v.y = fmaxf(v.y, 0.f);
            v.z = fmaxf(v.z, 0.f); v.w = fmaxf(v.w, 0.f);
        }
        if (OUTBF) {
            ushort4 u;
            u.x = f2bf(v.x); u.y = f2bf(v.y); u.z = f2bf(v.z); u.w = f2bf(v.w);
            *(ushort4*)((unsigned short*)C + gr) = u;
        } else {
            *(float4*)((float*)C + gr) = v;
        }
    }
}

// QKV (64x128 tile): z=0 -> q bf16 [B,S,768], z=1 -> k, z=2 -> V^T bf16 [B*H, 64, 512]
__global__ __launch_bounds__(256) void k_gemm_qkv_bf(const unsigned short* __restrict__ X,
                                                     const unsigned short* __restrict__ wq,
                                                     const unsigned short* __restrict__ wk,
                                                     const unsigned short* __restrict__ wv,
                                                     unsigned short* __restrict__ qo,
                                                     unsigned short* __restrict__ ko,
                                                     unsigned short* __restrict__ vt) {
    __shared__ __align__(16) char smem[2 * (64 + 128) * 64 * 2];  // 48KB; cbuf needs 33.8KB
    unsigned short* lsA = (unsigned short*)smem;
    unsigned short* lsB = lsA + 2 * 64 * 64;
    f32x4 acc[2][4] = {};
    int z = blockIdx.z;
    const unsigned short* Bm = z == 0 ? wq : (z == 1 ? wk : wv);
    int bm = blockIdx.x, bn = blockIdx.y;
    gemm_core_t<64, 128>(X, Bm, D_, bm, bn, lsA, lsB, acc);
    int t = threadIdx.x, lane = t & 63, w = t >> 6;
    int l15 = lane & 15, l4 = lane >> 4;
    int wr = (w >> 1) * 32, wc = (w & 1) * 64;
    if (z < 2) {
        unsigned short* C = z == 0 ? qo : ko;
        constexpr int BNP = 132;
        float* cb = (float*)smem;
        __syncthreads();
        #pragma unroll
        for (int i = 0; i < 2; ++i)
            #pragma unroll
            for (int r = 0; r < 4; ++r)
                #pragma unroll
                for (int j = 0; j < 4; ++j)
                    cb[(wr + i * 16 + l4 * 4 + r) * BNP + wc + j * 16 + l15] = acc[i][j][r];
        __syncthreads();
        int rr = t >> 5, cc = t & 31;            // 32 f4 per row, 8 rows per pass
        #pragma unroll
        for (int p = 0; p < 8; ++p) {
            int row = p * 8 + rr;
            float4 v = *(float4*)&cb[row * BNP + cc * 4];
            size_t gr = (size_t)(bm * 64 + row) * D_ + bn * 128 + cc * 4;
            ushort4 u;
            u.x = f2bf(v.x); u.y = f2bf(v.y); u.z = f2bf(v.z); u.w = f2bf(v.w);
            *(ushort4*)(C + gr) = u;
        }
    } else {
        // V^T: vt[((b*H + h)*64 + dv)*512 + s]
        #pragma unroll
        for (int i = 0; i < 2; ++i) {
            int row0 = bm * 64 + wr + i * 16 + l4 * 4;
            int b = row0 >> 9, s0 = row0 & 511;
            #pragma unroll
            for (int j = 0; j < 4; ++j) {
                int col = bn * 128 + wc + j * 16 + l15;
                int hh = col >> 6, dv = col & 63;
                ushort4 o4;
                o4.x = f2bf(acc[i][j][0]); o4.y = f2bf(acc[i][j][1]);
                o4.z = f2bf(acc[i][j][2]); o4.w = f2bf(acc[i][j][3]);
                *(ushort4*)(vt + (((size_t)b * H_ + hh) * 64 + dv) * S_ + s0) = o4;
            }
        }
    }
}

// ---------------- MFMA flash attention ----------------
// 2-deep K/V LDS pipeline; bias regs pipelined one tile ahead; mask folded to emask LDS.
__global__ __launch_bounds__(256) void k_attn_flash(const unsigned short* __restrict__ qb,
                                                    const unsigned short* __restrict__ kb,
                                                    const unsigned short* __restrict__ vtb,
                                                    const unsigned short* __restrict__ biasg,
                                                    const float* __restrict__ mask,
                                                    unsigned short* __restrict__ ctx) {
    __shared__ __align__(16) unsigned short Kt[2][64 * 64];
    __shared__ __align__(16) unsigned short Vt[2][64 * 64];
    __shared__ __align__(16) unsigned short Pt[4][16 * 64];
    __shared__ __align__(16) float emask[S_];

    int t = threadIdx.x, lane = t & 63, w = t >> 6;
    int l15 = lane & 15, l4 = lane >> 4;
    int bh = blockIdx.y;
    int b = bh / H_, hh = bh - b * H_;
    int qblk = blockIdx.x;
    int qloc = w * 16 + l15;
    int qg = qblk * 64 + qloc;

    bf16x8 qf[2];
    {
        const unsigned short* qp = qb + ((size_t)(b * S_ + qg)) * D_ + hh * DK_;
        qf[0] = *(const bf16x8*)(qp + l4 * 8);
        qf[1] = *(const bf16x8*)(qp + 32 + l4 * 8);
    }
    float mrun = -1e30f, lsum = 0.f;
    f32x4 cacc[4] = {};

    auto stage_kv = [&](int kt, int buf) {
        int kbase = kt * 64;
        #pragma unroll
        for (int c = 0; c < 2; ++c) {
            int off = (w * 2 + c) * 1024 + lane * 16;
            int row = off >> 7;
            int colb = (off & 127) ^ ((row & 7) << 4);
            GLDS(kb + ((size_t)(b * S_ + kbase + row)) * D_ + hh * DK_ + (colb >> 1),
                 (char*)Kt[buf] + off);
            GLDS(vtb + ((size_t)bh * 64 + row) * S_ + kbase + (colb >> 1),
                 (char*)Vt[buf] + off);
        }
    };

    const unsigned short* bprow = biasg + ((size_t)hh * S_ + qblk * 64 + qloc) * S_;

    stage_kv(0, 0);
    if (t < 128) {
        float4 m = ((const float4*)(mask + (size_t)b * S_))[t];
        float4 e;
        e.x = (1.f - m.x) * NEG_; e.y = (1.f - m.y) * NEG_;
        e.z = (1.f - m.z) * NEG_; e.w = (1.f - m.w) * NEG_;
        *(float4*)&emask[t * 4] = e;
    }
    ushort4 bnxt[4];
    #pragma unroll
    for (int j = 0; j < 4; ++j)
        bnxt[j] = *(const ushort4*)(bprow + j * 16 + l4 * 4);
    asm volatile("s_waitcnt lgkmcnt(0)" ::: "memory");   // emask writes done
    __builtin_amdgcn_s_barrier();

    constexpr int NT = S_ / 64;
    for (int kt = 0; kt < NT; ++kt) {
        int cur = kt & 1;
        int kbase = kt * 64;
        ushort4 bcur[4];
        #pragma unroll
        for (int j = 0; j < 4; ++j) bcur[j] = bnxt[j];

        if (kt < NT - 1) {
            stage_kv(kt + 1, cur ^ 1);
            asm volatile("s_waitcnt vmcnt(4)" ::: "memory");
        } else {
            asm volatile("s_waitcnt vmcnt(0)" ::: "memory");
        }
        __builtin_amdgcn_s_barrier();
        if (kt < NT - 1) {
            #pragma unroll
            for (int j = 0; j < 4; ++j)
                bnxt[j] = *(const ushort4*)(bprow + (kt + 1) * 64 + j * 16 + l4 * 4);
        }

        f32x4 sc[4] = {};
        __builtin_amdgcn_s_setprio(1);
        #pragma unroll
        for (int kk = 0; kk < 2; ++kk) {
            int kByte = kk * 64 + l4 * 16;
            #pragma unroll
            for (int j = 0; j < 4; ++j) {
                int r = j * 16 + l15;
                bf16x8 kf = *(const bf16x8*)((const char*)Kt[cur] + r * 128 + (kByte ^ ((r & 7) << 4)));
                sc[j] = __builtin_amdgcn_mfma_f32_16x16x32_bf16(kf, qf[kk], sc[j], 0, 0, 0);
            }
        }
        __builtin_amdgcn_s_setprio(0);

        float sv[4][4];
        float tmax = -1e30f;
        #pragma unroll
        for (int j = 0; j < 4; ++j) {
            float4 e4 = *(const float4*)&emask[kbase + j * 16 + l4 * 4];
            sv[j][0] = sc[j][0] + bf2f(bcur[j].x) + e4.x;
            sv[j][1] = sc[j][1] + bf2f(bcur[j].y) + e4.y;
            sv[j][2] = sc[j][2] + bf2f(bcur[j].z) + e4.z;
            sv[j][3] = sc[j][3] + bf2f(bcur[j].w) + e4.w;
            tmax = fmaxf(tmax, fmaxf(fmaxf(sv[j][0], sv[j][1]), fmaxf(sv[j][2], sv[j][3])));
        }
        tmax = fmaxf(tmax, __shfl_xor(tmax, 16, 64));
        tmax = fmaxf(tmax, __shfl_xor(tmax, 32, 64));
        float mnew = fmaxf(mrun, tmax);
        float scal = __expf(mrun - mnew);
        #pragma unroll
        for (int i = 0; i < 4; ++i) {
            cacc[i][0] *= scal; cacc[i][1] *= scal;
            cacc[i][2] *= scal; cacc[i][3] *= scal;
        }
        float psum = 0.f;
        unsigned pp[8];
        #pragma unroll
        for (int j = 0; j < 4; ++j) {
            float p0 = __expf(sv[j][0] - mnew), p1 = __expf(sv[j][1] - mnew);
            float p2 = __expf(sv[j][2] - mnew), p3 = __expf(sv[j][3] - mnew);
            psum += (p0 + p1) + (p2 + p3);
            pp[j * 2]     = (unsigned)f2bf(p0) | ((unsigned)f2bf(p1) << 16);
            pp[j * 2 + 1] = (unsigned)f2bf(p2) | ((unsigned)f2bf(p3) << 16);
        }
        lsum = lsum * scal + psum;
        mrun = mnew;
        unsigned short* P = Pt[w];
        #pragma unroll
        for (int j = 0; j < 4; ++j) {
            int base = l15 * 128 + ((j * 32 + l4 * 8) ^ ((l15 & 7) << 4));
            *(unsigned*)((char*)P + base) = pp[j * 2];
            *(unsigned*)((char*)P + base + 4) = pp[j * 2 + 1];
        }
        __builtin_amdgcn_s_setprio(1);
        #pragma unroll
        for (int kk = 0; kk < 2; ++kk) {
            int kByte = kk * 64 + l4 * 16;
            bf16x8 pf = *(const bf16x8*)((const char*)P + l15 * 128 + (kByte ^ ((l15 & 7) << 4)));
            #pragma unroll
            for (int i = 0; i < 4; ++i) {
                int rr = i * 16 + l15;
                bf16x8 vf = *(const bf16x8*)((const char*)Vt[cur] + rr * 128 + (kByte ^ ((rr & 7) << 4)));
                cacc[i] = __builtin_amdgcn_mfma_f32_16x16x32_bf16(vf, pf, cacc[i], 0, 0, 0);
            }
        }
        __builtin_amdgcn_s_setprio(0);
        asm volatile("s_waitcnt lgkmcnt(0)" ::: "memory");
        __builtin_amdgcn_s_barrier();
    }
    lsum += __shfl_xor(lsum, 16, 64);
    lsum += __shfl_xor(lsum, 32, 64);
    float inv = 1.f / lsum;
    unsigned short* cp = ctx + ((size_t)(b * S_ + qg)) * D_ + hh * DK_;
    #pragma unroll
    for (int i = 0; i < 4; ++i) {
        ushort4 o4;
        o4.x = f2bf(cacc[i][0] * inv); o4.y = f2bf(cacc[i][1] * inv);
        o4.z = f2bf(cacc[i][2] * inv); o4.w = f2bf(cacc[i][3] * inv);
        *(ushort4*)(cp + i * 16 + l4 * 4) = o4;
    }
}

// ---------------- launcher ----------------
extern "C" void kernel_launch(void* const* d_in, const int* in_sizes, int n_in,
                              void* d_out, int out_size, void* d_ws, size_t ws_size,
                              hipStream_t stream) {
    const int*   ids  = (const int*)d_in[0];
    const float* mask = (const float*)d_in[1];
    const float* ew   = (const float*)d_in[2];
    const float* ln1  = (const float*)d_in[3];
    const float* qw   = (const float*)d_in[4];
    const float* kw   = (const float*)d_in[5];
    const float* vw   = (const float*)d_in[6];
    const float* rbw  = (const float*)d_in[7];
    const float* ow   = (const float*)d_in[8];
    const float* ln2  = (const float*)d_in[9];
    const float* wiw  = (const float*)d_in[10];
    const float* wow  = (const float*)d_in[11];
    const float* flnw = (const float*)d_in[12];
    float* out = (float*)d_out;

    // ws layout (~136 MB of ~385 MB): h | biasg | wball(6 layers) | xbf(=ctxb) | qbB kbB vtb [+tail]
    char* p = (char*)d_ws;
    float* h = (float*)p;                        p += BSD_ * 4;
    unsigned short* biasg = (unsigned short*)p;  p += (size_t)H_ * S_ * S_ * 2;
    unsigned short* wball = (unsigned short*)p;  p += (size_t)L_ * WLAYER_ * 2;
    unsigned short* xbf   = (unsigned short*)p;  p += BSD_ * 2;
    unsigned short* ctxb  = xbf;                 // aliased: disjoint lifetimes
    unsigned short* qbB   = (unsigned short*)p;  p += BSD_ * 2;
    unsigned short* kbB   = (unsigned short*)p;  p += BSD_ * 2;
    unsigned short* vtb   = (unsigned short*)p;  p += BSD_ * 2;
    /* extra 6.3MB tail for ff */                p += BSD_ * 2;
    unsigned short* ff    = qbB;                 // 25.2MB spans qbB..tail, dead by FFN

    k_embed<<<BS_, 192, 0, stream>>>(ids, ew, h);
    k_posbias<<<(S_ * S_ + 255) / 256, 256, 0, stream>>>(rbw, biasg);
    k_wconv_all<<<(L_ * WLV4) / 256, 256, 0, stream>>>(qw, kw, vw, ow, wiw, wow, wball);

    for (int l = 0; l < L_; ++l) {
        const unsigned short* wl  = wball + (size_t)l * WLAYER_;
        const unsigned short* wq  = wl;
        const unsigned short* wk  = wl + 589824;
        const unsigned short* wv  = wl + 1179648;
        const unsigned short* wo  = wl + 1769472;
        const unsigned short* wwi = wl + 2359296;
        const unsigned short* wwo = wl + 4718592;

        k_rmsnorm<1><<<BS_, 256, 0, stream>>>(h, ln1 + (size_t)l * D_, xbf);
        k_gemm_qkv_bf<<<dim3(BS_ / 64, D_ / 128, 3), 256, 0, stream>>>(
            xbf, wq, wk, wv, qbB, kbB, vtb);
        k_attn_flash<<<dim3(S_ / 64, B_ * H_), 256, 0, stream>>>(
            qbB, kbB, vtb, biasg, mask, ctxb);
        k_gemm_t<64, 64, 1, 0, 0><<<dim3(BS_ / 64, D_ / 64), 256, 0, stream>>>(
            ctxb, wo, h, h, D_, D_);
        k_rmsnorm<1><<<BS_, 256, 0, stream>>>(h, ln2 + (size_t)l * D_, xbf);
        k_gemm_t<64, 128, 0, 1, 1><<<dim3(BS_ / 64, DFF_ / 128), 256, 0, stream>>>(
            xbf, wwi, nullptr, ff, DFF_, D_);
        k_gemm_t<64, 64, 1, 0, 0><<<dim3(BS_ / 64, D_ / 64), 256, 0, stream>>>(
            ff, wwo, h, h, D_, DFF_);
    }
    k_rmsnorm<0><<<BS_, 256, 0, stream>>>(h, flnw, out);
}